// Round 4
// baseline (500.794 us; speedup 1.0000x reference)
//
#include <hip/hip_runtime.h>
#include <hip/hip_bf16.h>
#include <cstddef>
#include <cstdint>

#define NN 4096
#define BB 128

using short8 = __attribute__((ext_vector_type(8))) short;
using f32x4  = __attribute__((ext_vector_type(4))) float;

// visible-prefix limits for folded row r: exclusive = S, inclusive = E
__device__ __forceinline__ void klims(int r, int& S, int& E) {
    if (r == 0) { S = 0; E = 1; return; }
    int j = (31 - __clz(r)) >> 1;
    int g = r >> (2 * j);
    S = g << (2 * j);
    E = (g + 1) << (2 * j);
}

// folded index n -> lattice site (row*64+col)
__device__ __forceinline__ int perm_site(int n) {
    if (n == 0) return 0;
    int j = (31 - __clz(n)) >> 1;
    int g = n >> (2 * j);
    int o = n - (g << (2 * j));
    int side = 1 << j;
    int rr = o >> j, cc = o & (side - 1);
    int i = 5 - j;
    int s = 1 << i, p = 1 << (i + 1);
    int r, c;
    if (g == 1)      { r = s + rr * p; c = s + cc * p; }
    else if (g == 2) { r = s + rr * p; c = cc * p;     }
    else             { r = rr * p;     c = s + cc * p; }
    return r * 64 + c;
}

// lattice site s -> folded index n
__device__ __forceinline__ int inv_site(int s) {
    if (s == 0) return 0;
    int r = s >> 6, c = s & 63;
    int ir = r ? __builtin_ctz(r) : 6;
    int ic = c ? __builtin_ctz(c) : 6;
    int i = ir < ic ? ir : ic;
    int j = 5 - i;
    int rb = (r >> i) & 1, cb = (c >> i) & 1;
    int g = rb ? (cb ? 1 : 2) : 3;
    return (g << (2 * j)) + ((r >> (i + 1)) << j) + (c >> (i + 1));
}

// fragment-order element index for activation storage [k][b] (bf16)
__device__ __forceinline__ size_t fidx(int k, int b) {
    return (size_t)(((k >> 5) * 8 + (b >> 4)) * 512 + ((k >> 2) & 3) * 128 +
                    (b & 15) * 8 + ((k >> 4) & 1) * 4 + (k & 3));
}

__device__ __forceinline__ unsigned short f2bf(float f) {
    __hip_bfloat16 h = __float2bfloat16(f);
    return __builtin_bit_cast(unsigned short, h);
}

// fold: xf_frag[n][b] = x[b][site(n)] as bf16, coalesced reads over x
__global__ void fold_k(const float* __restrict__ x, unsigned short* __restrict__ xf) {
    int gid = blockIdx.x * 256 + threadIdx.x;  // b*4096 + s
    int b = gid >> 12, s = gid & 4095;
    float v = x[gid];
    int n = inv_site(s);
    xf[fidx(n, b)] = f2bf(v);
}

// Masked GEMM, register-streaming + 2-deep W prefetch.
// out[m][b] = act(sum_k W[m][k]*A[k][b] + bias)
// A: bf16 fragment-order (fidx), W: fp32 row-major [M][Ktot].
// 16 rows per block; 8 waves split K round-robin (64-k steps); LDS reduce at end.
// MODE 0: prelu -> bf16 frag-order store.  MODE 1: sigmoid + unfold scatter -> [B][N] fp32.
template <bool EXCL, int MODE>
__global__ __launch_bounds__(512, 4) void made_gemm3(
        const unsigned short* __restrict__ A, const float* __restrict__ W,
        const float* __restrict__ bias, const float* __restrict__ alpha,
        void* __restrict__ outp, int M, int Ktot, int nseg) {
    __shared__ f32x4 red[8 * 8 * 64];  // [wave][q][lane] = 64 KB

    const int tid  = threadIdx.x;
    const int wid  = tid >> 6;
    const int lane = tid & 63;
    const int r0   = M - 16 - (int)blockIdx.x * 16;   // reversed: heavy tiles first
    const int r_ch = r0 & (NN - 1);
    const int row  = lane & 15;      // W row within tile
    const int kq   = lane >> 4;      // k-quad within fragment

    int S, E;
    klims(r_ch + row, S, E);
    const int kl = EXCL ? S : E;     // per-row seg-local prefix limit
    klims(r_ch + 15, S, E);
    const int kmax = EXCL ? S : E;   // tile max (monotone in r)
    const int nkt = (kmax + 63) >> 6;
    const int nt  = nseg * nkt;
    const bool uni = (r_ch >= 64);

    f32x4 acc[8] = {};
    const float* wrow = W + (size_t)(r0 + row) * Ktot + kq * 4;

    float4 wbA[4], wbB[4];

// issue next k-step's W loads into buffer WB (4 x dwordx4 per lane)
#define ISSUE_W(T, WB)                                                        \
    {                                                                         \
        int sg_ = (nseg == 2 && (T) >= nkt) ? 1 : 0;                          \
        const float* wp_ = wrow + sg_ * NN + (((T) - sg_ * nkt) << 6);        \
        WB[0] = *(const float4*)(wp_);                                        \
        WB[1] = *(const float4*)(wp_ + 16);                                   \
        WB[2] = *(const float4*)(wp_ + 32);                                   \
        WB[3] = *(const float4*)(wp_ + 48);                                   \
    }

// one 64-k step: A loads (batch 1) -> W prefetch (t+8) -> A loads (batch 2)
// -> mask+cvt resident W -> 16 MFMA
#define COMPUTE(T, WB, PRE, TN, WN)                                           \
    {                                                                         \
        int sg_ = (nseg == 2 && (T) >= nkt) ? 1 : 0;                          \
        int kb_ = ((T) - sg_ * nkt) << 6;                                     \
        const unsigned short* ab_ =                                           \
            A + (size_t)(sg_ * NN + kb_) * 128 + lane * 8;                    \
        short8 av_[16];                                                       \
        _Pragma("unroll")                                                     \
        for (int q_ = 0; q_ < 4; ++q_) {                                      \
            av_[2 * q_]     = *(const short8*)(ab_ + q_ * 512);               \
            av_[2 * q_ + 1] = *(const short8*)(ab_ + 4096 + q_ * 512);        \
        }                                                                     \
        if (PRE) ISSUE_W(TN, WN);                                             \
        _Pragma("unroll")                                                     \
        for (int q_ = 4; q_ < 8; ++q_) {                                      \
            av_[2 * q_]     = *(const short8*)(ab_ + q_ * 512);               \
            av_[2 * q_ + 1] = *(const short8*)(ab_ + 4096 + q_ * 512);        \
        }                                                                     \
        float wv_[16];                                                        \
        _Pragma("unroll")                                                     \
        for (int i_ = 0; i_ < 4; ++i_) {                                      \
            wv_[4 * i_ + 0] = WB[i_].x;                                       \
            wv_[4 * i_ + 1] = WB[i_].y;                                       \
            wv_[4 * i_ + 2] = WB[i_].z;                                       \
            wv_[4 * i_ + 3] = WB[i_].w;                                       \
        }                                                                     \
        if (!uni) {                                                           \
            int k0_ = kb_ + kq * 4;                                           \
            _Pragma("unroll")                                                 \
            for (int i_ = 0; i_ < 4; ++i_) {                                  \
                _Pragma("unroll")                                             \
                for (int j_ = 0; j_ < 4; ++j_)                                \
                    if (k0_ + i_ * 16 + j_ >= kl) wv_[4 * i_ + j_] = 0.0f;    \
            }                                                                 \
        }                                                                     \
        short8 wf0_, wf1_;                                                    \
        _Pragma("unroll")                                                     \
        for (int e_ = 0; e_ < 8; ++e_) {                                      \
            wf0_[e_] = (short)f2bf(wv_[e_]);                                  \
            wf1_[e_] = (short)f2bf(wv_[8 + e_]);                              \
        }                                                                     \
        _Pragma("unroll")                                                     \
        for (int q_ = 0; q_ < 8; ++q_) {                                      \
            acc[q_] = __builtin_amdgcn_mfma_f32_16x16x32_bf16(                \
                wf0_, av_[2 * q_], acc[q_], 0, 0, 0);                         \
            acc[q_] = __builtin_amdgcn_mfma_f32_16x16x32_bf16(                \
                wf1_, av_[2 * q_ + 1], acc[q_], 0, 0, 0);                     \
        }                                                                     \
    }

    int t = wid;
    if (t < nt) {
        ISSUE_W(t, wbA);
        while (true) {
            int tn = t + 8;
            bool pre = tn < nt;
            COMPUTE(t, wbA, pre, tn, wbB);
            if (!pre) break;
            t = tn;
            tn = t + 8;
            pre = tn < nt;
            COMPUTE(t, wbB, pre, tn, wbA);
            if (!pre) break;
            t = tn;
        }
    }
#undef ISSUE_W
#undef COMPUTE

    // cross-wave K reduce (conflict-free f32x4 at lane*16)
#pragma unroll
    for (int q = 0; q < 8; ++q) red[(wid * 8 + q) * 64 + lane] = acc[q];
    __syncthreads();
    const int q = wid;
    f32x4 sum = red[q * 64 + lane];
#pragma unroll
    for (int w = 1; w < 8; ++w) sum += red[(w * 8 + q) * 64 + lane];

    const int m0 = r0 + kq * 4;
    const int b  = q * 16 + row;
    if (MODE == 0) {
        f32x4 bv = *(const f32x4*)&bias[m0];
        f32x4 av = *(const f32x4*)&alpha[m0];
        ushort4 st;
        float v;
        v = sum[0] + bv[0]; v = fmaxf(v, 0.0f) + av[0] * fminf(v, 0.0f); st.x = f2bf(v);
        v = sum[1] + bv[1]; v = fmaxf(v, 0.0f) + av[1] * fminf(v, 0.0f); st.y = f2bf(v);
        v = sum[2] + bv[2]; v = fmaxf(v, 0.0f) + av[2] * fminf(v, 0.0f); st.z = f2bf(v);
        v = sum[3] + bv[3]; v = fmaxf(v, 0.0f) + av[3] * fminf(v, 0.0f); st.w = f2bf(v);
        unsigned short* hout = (unsigned short*)outp;
        *(ushort4*)&hout[fidx(m0, b)] = st;   // 4 consecutive j-slots: one 8B store
    } else {
        float* out = (float*)outp;
        f32x4 bv = *(const f32x4*)&bias[m0];
#pragma unroll
        for (int i = 0; i < 4; ++i) {
            int m = m0 + i;
            float v = sum[i] + bv[i];
            float sg = 1.0f / (1.0f + __expf(-v));
            if (m == 0) sg = 0.5f;
            out[(size_t)b * NN + perm_site(m)] = sg;
        }
    }
}

extern "C" void kernel_launch(void* const* d_in, const int* in_sizes, int n_in,
                              void* d_out, int out_size, void* d_ws, size_t ws_size,
                              hipStream_t stream) {
    const float* x  = (const float*)d_in[0];
    const float* W0 = (const float*)d_in[1];
    const float* b0 = (const float*)d_in[2];
    const float* a1 = (const float*)d_in[3];
    const float* W1 = (const float*)d_in[4];
    const float* b1 = (const float*)d_in[5];
    const float* a2 = (const float*)d_in[6];
    const float* W2 = (const float*)d_in[7];
    const float* b2 = (const float*)d_in[8];

    char* ws = (char*)d_ws;
    unsigned short* xf = (unsigned short*)ws;                // 1 MB  (4096x128 bf16, frag order)
    unsigned short* h0 = (unsigned short*)(ws + (1 << 20));  // 2 MB  (8192x128)
    unsigned short* h1 = (unsigned short*)(ws + (3 << 20));  // 2 MB  (8192x128)

    fold_k<<<2048, 256, 0, stream>>>(x, xf);
    made_gemm3<true, 0><<<512, 512, 0, stream>>>(xf, W0, b0, a1, h0, 2 * NN, NN, 1);
    made_gemm3<false, 0><<<512, 512, 0, stream>>>(h0, W1, b1, a2, h1, 2 * NN, 2 * NN, 2);
    made_gemm3<false, 1><<<256, 512, 0, stream>>>(h1, W2, b2, nullptr, (float*)d_out, NN, 2 * NN, 2);
}

// Round 5
// 192.241 us; speedup vs baseline: 2.6050x; 2.6050x over previous
//
#include <hip/hip_runtime.h>
#include <hip/hip_bf16.h>
#include <cstddef>
#include <cstdint>

#define NN 4096
#define BB 128

using short8 = __attribute__((ext_vector_type(8))) short;
using f32x4  = __attribute__((ext_vector_type(4))) float;

// visible-prefix limits for folded row r: exclusive = S, inclusive = E
__device__ __forceinline__ void klims(int r, int& S, int& E) {
    if (r == 0) { S = 0; E = 1; return; }
    int j = (31 - __clz(r)) >> 1;
    int g = r >> (2 * j);
    S = g << (2 * j);
    E = (g + 1) << (2 * j);
}

// folded index n -> lattice site (row*64+col)
__device__ __forceinline__ int perm_site(int n) {
    if (n == 0) return 0;
    int j = (31 - __clz(n)) >> 1;
    int g = n >> (2 * j);
    int o = n - (g << (2 * j));
    int side = 1 << j;
    int rr = o >> j, cc = o & (side - 1);
    int i = 5 - j;
    int s = 1 << i, p = 1 << (i + 1);
    int r, c;
    if (g == 1)      { r = s + rr * p; c = s + cc * p; }
    else if (g == 2) { r = s + rr * p; c = cc * p;     }
    else             { r = rr * p;     c = s + cc * p; }
    return r * 64 + c;
}

// lattice site s -> folded index n
__device__ __forceinline__ int inv_site(int s) {
    if (s == 0) return 0;
    int r = s >> 6, c = s & 63;
    int ir = r ? __builtin_ctz(r) : 6;
    int ic = c ? __builtin_ctz(c) : 6;
    int i = ir < ic ? ir : ic;
    int j = 5 - i;
    int rb = (r >> i) & 1, cb = (c >> i) & 1;
    int g = rb ? (cb ? 1 : 2) : 3;
    return (g << (2 * j)) + ((r >> (i + 1)) << j) + (c >> (i + 1));
}

// fragment-order element index for activation storage [k][b] (bf16)
__device__ __forceinline__ size_t fidx(int k, int b) {
    return (size_t)(((k >> 5) * 8 + (b >> 4)) * 512 + ((k >> 2) & 3) * 128 +
                    (b & 15) * 8 + ((k >> 4) & 1) * 4 + (k & 3));
}

__device__ __forceinline__ unsigned short f2bf(float f) {
    __hip_bfloat16 h = __float2bfloat16(f);
    return __builtin_bit_cast(unsigned short, h);
}

// fold: xf_frag[n][b] = x[b][site(n)] as bf16, coalesced reads over x
__global__ void fold_k(const float* __restrict__ x, unsigned short* __restrict__ xf) {
    int gid = blockIdx.x * 256 + threadIdx.x;  // b*4096 + s
    int b = gid >> 12, s = gid & 4095;
    float v = x[gid];
    int n = inv_site(s);
    xf[fidx(n, b)] = f2bf(v);
}

// Masked GEMM, MT=128: 8 waves each own a 16-row tile sharing the A k-stream.
// Block-level k-split: block (tile, chunk) covers t in [chunk*nt/nsplit, (chunk+1)*nt/nsplit).
// Writes fp32 partials: partial[chunk][m][b].
template <bool EXCL>
__global__ __launch_bounds__(512, 2) void made_gemm5(
        const unsigned short* __restrict__ A, const float* __restrict__ W,
        float* __restrict__ partial, int M, int Ktot, int nseg, int nsplit) {
    const int tid  = threadIdx.x;
    const int wid  = tid >> 6;
    const int lane = tid & 63;
    const int tile  = (int)blockIdx.x / nsplit;
    const int chunk = (int)blockIdx.x - tile * nsplit;
    const int r0  = M - 128 - tile * 128;    // reversed: heavy tiles first
    const int rw0 = r0 + wid * 16;           // this wave's 16-row base
    const int rch = rw0 & (NN - 1);
    const int row = lane & 15;
    const int kq  = lane >> 4;

    int S, E;
    klims(rch + row, S, E);
    const int kl = EXCL ? S : E;             // per-row seg-local prefix limit
    klims(rch + 15, S, E);
    const int kmax = EXCL ? S : E;           // tile max (monotone in r)
    const int nkt = (kmax + 63) >> 6;
    const int nt  = nseg * nkt;
    const int t0  = (chunk * nt) / nsplit;
    const int t1  = ((chunk + 1) * nt) / nsplit;
    const bool uni = (rch >= 64);

    f32x4 acc[8] = {};
    const float* wrow = W + (size_t)(rw0 + row) * Ktot + kq * 4;

    float4 wbA[4], wbB[4];

#define ISSUE_W(T, WB)                                                        \
    {                                                                         \
        int sg_ = (nseg == 2 && (T) >= nkt) ? 1 : 0;                          \
        const float* wp_ = wrow + sg_ * NN + (((T) - sg_ * nkt) << 6);        \
        WB[0] = *(const float4*)(wp_);                                        \
        WB[1] = *(const float4*)(wp_ + 16);                                   \
        WB[2] = *(const float4*)(wp_ + 32);                                   \
        WB[3] = *(const float4*)(wp_ + 48);                                   \
    }

// one 64-k step: issue all A loads, then prefetch W(t+1), then mask+cvt resident
// W(t), then 16 MFMA. A issued before W(t+1) => consuming A never drains prefetch.
#define COMPUTE(T, WB, PRE, WN)                                               \
    {                                                                         \
        int sg_ = (nseg == 2 && (T) >= nkt) ? 1 : 0;                          \
        int kb_ = ((T) - sg_ * nkt) << 6;                                     \
        const unsigned short* ab_ =                                           \
            A + (size_t)((sg_ * NN + kb_) >> 5) * 4096 + lane * 8;            \
        short8 av_[16];                                                       \
        _Pragma("unroll")                                                     \
        for (int q_ = 0; q_ < 8; ++q_) {                                      \
            av_[2 * q_]     = *(const short8*)(ab_ + q_ * 512);               \
            av_[2 * q_ + 1] = *(const short8*)(ab_ + 4096 + q_ * 512);        \
        }                                                                     \
        if (PRE) ISSUE_W((T) + 1, WN);                                        \
        float wv_[16];                                                        \
        _Pragma("unroll")                                                     \
        for (int i_ = 0; i_ < 4; ++i_) {                                      \
            wv_[4 * i_ + 0] = WB[i_].x;                                       \
            wv_[4 * i_ + 1] = WB[i_].y;                                       \
            wv_[4 * i_ + 2] = WB[i_].z;                                       \
            wv_[4 * i_ + 3] = WB[i_].w;                                       \
        }                                                                     \
        if (!uni) {                                                           \
            int k0_ = kb_ + kq * 4;                                           \
            _Pragma("unroll")                                                 \
            for (int i_ = 0; i_ < 4; ++i_) {                                  \
                _Pragma("unroll")                                             \
                for (int j_ = 0; j_ < 4; ++j_)                                \
                    if (k0_ + i_ * 16 + j_ >= kl) wv_[4 * i_ + j_] = 0.0f;    \
            }                                                                 \
        }                                                                     \
        short8 wf0_, wf1_;                                                    \
        _Pragma("unroll")                                                     \
        for (int e_ = 0; e_ < 8; ++e_) {                                      \
            wf0_[e_] = (short)f2bf(wv_[e_]);                                  \
            wf1_[e_] = (short)f2bf(wv_[8 + e_]);                              \
        }                                                                     \
        _Pragma("unroll")                                                     \
        for (int q_ = 0; q_ < 8; ++q_) {                                      \
            acc[q_] = __builtin_amdgcn_mfma_f32_16x16x32_bf16(                \
                wf0_, av_[2 * q_], acc[q_], 0, 0, 0);                         \
            acc[q_] = __builtin_amdgcn_mfma_f32_16x16x32_bf16(                \
                wf1_, av_[2 * q_ + 1], acc[q_], 0, 0, 0);                     \
        }                                                                     \
    }

    if (t0 < t1) {
        int t = t0;
        ISSUE_W(t, wbA);
        while (true) {
            bool pre = (t + 1 < t1);
            COMPUTE(t, wbA, pre, wbB);
            if (!pre) break;
            ++t;
            pre = (t + 1 < t1);
            COMPUTE(t, wbB, pre, wbA);
            if (!pre) break;
            ++t;
        }
    }
#undef ISSUE_W
#undef COMPUTE

    // write fp32 partials (always, incl. zero-work chunks: buffer starts poisoned)
    float* pc = partial + ((size_t)chunk * M + rw0 + kq * 4) * BB + row;
#pragma unroll
    for (int q = 0; q < 8; ++q)
#pragma unroll
        for (int i = 0; i < 4; ++i)
            pc[(size_t)i * BB + q * 16] = acc[q][i];
}

// reduce partials + bias + prelu -> bf16 fragment-order activations
__global__ void reduce01_k(const float* __restrict__ p, const float* __restrict__ bias,
                           const float* __restrict__ alpha, unsigned short* __restrict__ h,
                           int M, int nsplit) {
    int gid = blockIdx.x * 256 + threadIdx.x;   // (M/4)*128 threads
    int m0 = (gid >> 7) << 2;
    int b  = gid & 127;
    f32x4 v = {};
    for (int c = 0; c < nsplit; ++c) {
        const float* pc = p + ((size_t)c * M + m0) * BB + b;
        v[0] += pc[0];
        v[1] += pc[BB];
        v[2] += pc[2 * BB];
        v[3] += pc[3 * BB];
    }
    ushort4 st;
    float t;
    t = v[0] + bias[m0 + 0]; t = fmaxf(t, 0.f) + alpha[m0 + 0] * fminf(t, 0.f); st.x = f2bf(t);
    t = v[1] + bias[m0 + 1]; t = fmaxf(t, 0.f) + alpha[m0 + 1] * fminf(t, 0.f); st.y = f2bf(t);
    t = v[2] + bias[m0 + 2]; t = fmaxf(t, 0.f) + alpha[m0 + 2] * fminf(t, 0.f); st.z = f2bf(t);
    t = v[3] + bias[m0 + 3]; t = fmaxf(t, 0.f) + alpha[m0 + 3] * fminf(t, 0.f); st.w = f2bf(t);
    *(ushort4*)&h[fidx(m0, b)] = st;
}

// reduce partials + bias + sigmoid + unfold scatter -> out[b][site]
__global__ void reduce2_k(const float* __restrict__ p, const float* __restrict__ b2,
                          float* __restrict__ out, int nsplit) {
    int gid = blockIdx.x * 256 + threadIdx.x;   // NN*BB threads, n-major
    int n = gid >> 7;
    int b = gid & 127;
    float v = 0.0f;
    for (int c = 0; c < nsplit; ++c) v += p[((size_t)c * NN + n) * BB + b];
    v += b2[n];
    float sg = 1.0f / (1.0f + __expf(-v));
    if (n == 0) sg = 0.5f;
    out[(size_t)b * NN + perm_site(n)] = sg;
}

extern "C" void kernel_launch(void* const* d_in, const int* in_sizes, int n_in,
                              void* d_out, int out_size, void* d_ws, size_t ws_size,
                              hipStream_t stream) {
    const float* x  = (const float*)d_in[0];
    const float* W0 = (const float*)d_in[1];
    const float* b0 = (const float*)d_in[2];
    const float* a1 = (const float*)d_in[3];
    const float* W1 = (const float*)d_in[4];
    const float* b1 = (const float*)d_in[5];
    const float* a2 = (const float*)d_in[6];
    const float* W2 = (const float*)d_in[7];
    const float* b2 = (const float*)d_in[8];

    char* ws = (char*)d_ws;
    unsigned short* xf = (unsigned short*)ws;                 // 1 MB
    unsigned short* h0 = (unsigned short*)(ws + (1 << 20));   // 2 MB
    unsigned short* h1 = (unsigned short*)(ws + (3 << 20));   // 2 MB
    float*          pp = (float*)(ws + (5 << 20));            // up to 16 MB partials

    size_t avail = ws_size > (5u << 20) ? ws_size - (5u << 20) : 0;
    int ns01, ns2;
    if (avail >= (16u << 20))      { ns01 = 4; ns2 = 8; }
    else if (avail >= (8u << 20))  { ns01 = 2; ns2 = 4; }
    else                           { ns01 = 1; ns2 = 2; }

    fold_k<<<2048, 256, 0, stream>>>(x, xf);

    made_gemm5<true><<<64 * ns01, 512, 0, stream>>>(xf, W0, pp, 2 * NN, NN, 1, ns01);
    reduce01_k<<<1024, 256, 0, stream>>>(pp, b0, a1, h0, 2 * NN, ns01);

    made_gemm5<false><<<64 * ns01, 512, 0, stream>>>(h0, W1, pp, 2 * NN, 2 * NN, 2, ns01);
    reduce01_k<<<1024, 256, 0, stream>>>(pp, b1, a2, h1, 2 * NN, ns01);

    made_gemm5<false><<<32 * ns2, 512, 0, stream>>>(h1, W2, pp, NN, 2 * NN, 2, ns2);
    reduce2_k<<<2048, 256, 0, stream>>>(pp, b2, (float*)d_out, ns2);
}

// Round 6
// 191.909 us; speedup vs baseline: 2.6095x; 1.0017x over previous
//
#include <hip/hip_runtime.h>
#include <hip/hip_bf16.h>
#include <cstddef>
#include <cstdint>

#define NN 4096
#define BB 128

using short8 = __attribute__((ext_vector_type(8))) short;
using f32x4  = __attribute__((ext_vector_type(4))) float;

// visible-prefix limits for folded row r: exclusive = S, inclusive = E
__device__ __forceinline__ void klims(int r, int& S, int& E) {
    if (r == 0) { S = 0; E = 1; return; }
    int j = (31 - __clz(r)) >> 1;
    int g = r >> (2 * j);
    S = g << (2 * j);
    E = (g + 1) << (2 * j);
}

// folded index n -> lattice site (row*64+col)
__device__ __forceinline__ int perm_site(int n) {
    if (n == 0) return 0;
    int j = (31 - __clz(n)) >> 1;
    int g = n >> (2 * j);
    int o = n - (g << (2 * j));
    int side = 1 << j;
    int rr = o >> j, cc = o & (side - 1);
    int i = 5 - j;
    int s = 1 << i, p = 1 << (i + 1);
    int r, c;
    if (g == 1)      { r = s + rr * p; c = s + cc * p; }
    else if (g == 2) { r = s + rr * p; c = cc * p;     }
    else             { r = rr * p;     c = s + cc * p; }
    return r * 64 + c;
}

// lattice site s -> folded index n
__device__ __forceinline__ int inv_site(int s) {
    if (s == 0) return 0;
    int r = s >> 6, c = s & 63;
    int ir = r ? __builtin_ctz(r) : 6;
    int ic = c ? __builtin_ctz(c) : 6;
    int i = ir < ic ? ir : ic;
    int j = 5 - i;
    int rb = (r >> i) & 1, cb = (c >> i) & 1;
    int g = rb ? (cb ? 1 : 2) : 3;
    return (g << (2 * j)) + ((r >> (i + 1)) << j) + (c >> (i + 1));
}

// fragment-order element index for activation storage [k][b] (bf16)
__device__ __forceinline__ size_t fidx(int k, int b) {
    return (size_t)(((k >> 5) * 8 + (b >> 4)) * 512 + ((k >> 2) & 3) * 128 +
                    (b & 15) * 8 + ((k >> 4) & 1) * 4 + (k & 3));
}

__device__ __forceinline__ unsigned short f2bf(float f) {
    __hip_bfloat16 h = __float2bfloat16(f);
    return __builtin_bit_cast(unsigned short, h);
}

// per-tile k-step count (tile-level kmax from its top row), uniform helper
__device__ __forceinline__ int tile_nt(int M, int tile, int nseg, int excl) {
    int r_top = (M - 1 - tile * 128) & (NN - 1);
    int S, E;
    klims(r_top, S, E);
    int kmax = excl ? S : E;
    return nseg * ((kmax + 63) >> 6);
}

// fold: xf_frag[n][b] = x[b][site(n)] as bf16, coalesced reads over x
__global__ void fold_k(const float* __restrict__ x, unsigned short* __restrict__ xf) {
    int gid = blockIdx.x * 256 + threadIdx.x;  // b*4096 + s
    int b = gid >> 12, s = gid & 4095;
    float v = x[gid];
    int n = inv_site(s);
    xf[fidx(n, b)] = f2bf(v);
}

// Masked GEMM, flattened work queue: block = (tile of 128 rows, CHUNK k-steps).
// 8 waves x 16 rows; per-wave prefix masking at W load; fp32 partial at blockIdx slot.
template <bool EXCL>
__global__ __launch_bounds__(512, 2) void made_gemm6(
        const unsigned short* __restrict__ A, const float* __restrict__ W,
        float* __restrict__ partial, int M, int Ktot, int nseg, int CH) {
    // uniform block -> (tile, chunk) lookup
    int b = (int)blockIdx.x, tile = 0, base = 0, nt = 0;
    for (;;) {
        nt = tile_nt(M, tile, nseg, EXCL ? 1 : 0);
        int cnt = (nt + CH - 1) / CH;
        if (b < base + cnt) break;
        base += cnt;
        ++tile;
    }
    const int nkt = nt / nseg;
    const int t0 = (b - base) * CH;
    const int t1 = (t0 + CH < nt) ? t0 + CH : nt;

    const int tid  = threadIdx.x;
    const int wid  = tid >> 6;
    const int lane = tid & 63;
    const int r0   = M - 128 - tile * 128;
    const int rw0  = r0 + wid * 16;
    const int rch  = rw0 & (NN - 1);
    const int row  = lane & 15;
    const int kq   = lane >> 4;

    int S, E;
    klims(rch + row, S, E);
    const int kl = EXCL ? S : E;        // this lane-row's seg-local prefix limit
    klims(rch, S, E);
    const int wkmin = EXCL ? S : E;     // wave row-0 limit (monotone min)

    f32x4 acc[8] = {};
    const float* wrow = W + (size_t)(rw0 + row) * Ktot + kq * 4;

    float4 wbA[4], wbB[4];

#define ISSUE_W(T, WB)                                                        \
    {                                                                         \
        int sg_ = (nseg == 2 && (T) >= nkt) ? 1 : 0;                          \
        const float* wp_ = wrow + sg_ * NN + (((T) - sg_ * nkt) << 6);        \
        WB[0] = *(const float4*)(wp_);                                        \
        WB[1] = *(const float4*)(wp_ + 16);                                   \
        WB[2] = *(const float4*)(wp_ + 32);                                   \
        WB[3] = *(const float4*)(wp_ + 48);                                   \
    }

#define COMPUTE(T, WB, PRE, WN)                                               \
    {                                                                         \
        int sg_ = (nseg == 2 && (T) >= nkt) ? 1 : 0;                          \
        int kb_ = ((T) - sg_ * nkt) << 6;                                     \
        const unsigned short* ab_ =                                           \
            A + (size_t)((sg_ * NN + kb_) >> 5) * 4096 + lane * 8;            \
        short8 av_[16];                                                       \
        _Pragma("unroll")                                                     \
        for (int q_ = 0; q_ < 8; ++q_) {                                      \
            av_[2 * q_]     = *(const short8*)(ab_ + q_ * 512);               \
            av_[2 * q_ + 1] = *(const short8*)(ab_ + 4096 + q_ * 512);        \
        }                                                                     \
        if (PRE) ISSUE_W((T) + 1, WN);                                        \
        float wv_[16];                                                        \
        _Pragma("unroll")                                                     \
        for (int i_ = 0; i_ < 4; ++i_) {                                      \
            wv_[4 * i_ + 0] = WB[i_].x;                                       \
            wv_[4 * i_ + 1] = WB[i_].y;                                       \
            wv_[4 * i_ + 2] = WB[i_].z;                                       \
            wv_[4 * i_ + 3] = WB[i_].w;                                       \
        }                                                                     \
        if (kb_ + 64 > wkmin) {                                               \
            int k0_ = kb_ + kq * 4;                                           \
            _Pragma("unroll")                                                 \
            for (int i_ = 0; i_ < 4; ++i_) {                                  \
                _Pragma("unroll")                                             \
                for (int j_ = 0; j_ < 4; ++j_)                                \
                    if (k0_ + i_ * 16 + j_ >= kl) wv_[4 * i_ + j_] = 0.0f;    \
            }                                                                 \
        }                                                                     \
        short8 wf0_, wf1_;                                                    \
        _Pragma("unroll")                                                     \
        for (int e_ = 0; e_ < 8; ++e_) {                                      \
            wf0_[e_] = (short)f2bf(wv_[e_]);                                  \
            wf1_[e_] = (short)f2bf(wv_[8 + e_]);                              \
        }                                                                     \
        _Pragma("unroll")                                                     \
        for (int q_ = 0; q_ < 8; ++q_) {                                      \
            acc[q_] = __builtin_amdgcn_mfma_f32_16x16x32_bf16(                \
                wf0_, av_[2 * q_], acc[q_], 0, 0, 0);                         \
            acc[q_] = __builtin_amdgcn_mfma_f32_16x16x32_bf16(                \
                wf1_, av_[2 * q_ + 1], acc[q_], 0, 0, 0);                     \
        }                                                                     \
    }

    {
        int t = t0;
        ISSUE_W(t, wbA);
        while (true) {
            bool pre = (t + 1 < t1);
            COMPUTE(t, wbA, pre, wbB);
            if (!pre) break;
            ++t;
            pre = (t + 1 < t1);
            COMPUTE(t, wbB, pre, wbA);
            if (!pre) break;
            ++t;
        }
    }
#undef ISSUE_W
#undef COMPUTE

    // fp32 partial tile [128 rows][128 b] at this block's slot
    float* pc = partial + (size_t)blockIdx.x * 16384 + (wid * 16 + kq * 4) * 128 + row;
#pragma unroll
    for (int q = 0; q < 8; ++q)
#pragma unroll
        for (int i = 0; i < 4; ++i)
            pc[(size_t)i * 128 + q * 16] = acc[q][i];
}

// reduce partial slots + bias + prelu -> bf16 fragment-order activations
__global__ void reduce01_k(const float* __restrict__ p, const float* __restrict__ bias,
                           const float* __restrict__ alpha, unsigned short* __restrict__ h,
                           int M, int nseg, int excl, int CH) {
    int gid = blockIdx.x * 256 + threadIdx.x;   // (M/4)*128 threads
    int m0 = (gid >> 7) << 2;
    int b  = gid & 127;
    int tile_m = (M - 128 - (m0 & ~127)) >> 7;
    int basep = 0, cntm = 0;
    for (int tt = 0; tt <= tile_m; ++tt) {
        int nt = tile_nt(M, tt, nseg, excl);
        int cnt = (nt + CH - 1) / CH;
        if (tt == tile_m) cntm = cnt;
        else basep += cnt;
    }
    const float* ps = p + (size_t)basep * 16384 + (m0 & 127) * 128 + b;
    f32x4 v = {};
    for (int s = 0; s < cntm; ++s) {
        v[0] += ps[0];
        v[1] += ps[128];
        v[2] += ps[256];
        v[3] += ps[384];
        ps += 16384;
    }
    ushort4 st;
    float t;
    t = v[0] + bias[m0 + 0]; t = fmaxf(t, 0.f) + alpha[m0 + 0] * fminf(t, 0.f); st.x = f2bf(t);
    t = v[1] + bias[m0 + 1]; t = fmaxf(t, 0.f) + alpha[m0 + 1] * fminf(t, 0.f); st.y = f2bf(t);
    t = v[2] + bias[m0 + 2]; t = fmaxf(t, 0.f) + alpha[m0 + 2] * fminf(t, 0.f); st.z = f2bf(t);
    t = v[3] + bias[m0 + 3]; t = fmaxf(t, 0.f) + alpha[m0 + 3] * fminf(t, 0.f); st.w = f2bf(t);
    *(ushort4*)&h[fidx(m0, b)] = st;
}

// reduce partial slots + bias + sigmoid + unfold scatter -> out[b][site]
__global__ void reduce2_k(const float* __restrict__ p, const float* __restrict__ b2,
                          float* __restrict__ out, int CH) {
    int gid = blockIdx.x * 256 + threadIdx.x;   // NN*BB threads, n-major
    int n = gid >> 7;
    int b = gid & 127;
    int tile_m = (NN - 128 - (n & ~127)) >> 7;
    int basep = 0, cntm = 0;
    for (int tt = 0; tt <= tile_m; ++tt) {
        int nt = tile_nt(NN, tt, 2, 0);
        int cnt = (nt + CH - 1) / CH;
        if (tt == tile_m) cntm = cnt;
        else basep += cnt;
    }
    const float* ps = p + (size_t)basep * 16384 + (n & 127) * 128 + b;
    float v = 0.0f;
    for (int s = 0; s < cntm; ++s) { v += *ps; ps += 16384; }
    v += b2[n];
    float sg = 1.0f / (1.0f + __expf(-v));
    if (n == 0) sg = 0.5f;
    out[(size_t)b * NN + perm_site(n)] = sg;
}

// ---------------- host ----------------
static inline void h_klims(int r, int& S, int& E) {
    if (r == 0) { S = 0; E = 1; return; }
    int j = (31 - __builtin_clz((unsigned)r)) >> 1;
    int g = r >> (2 * j);
    S = g << (2 * j);
    E = (g + 1) << (2 * j);
}

static inline int grid_for(int M, int nseg, int excl, int CH) {
    int nb = 0;
    for (int tile = 0; tile < M / 128; ++tile) {
        int r_top = (M - 1 - tile * 128) & (NN - 1);
        int S, E;
        h_klims(r_top, S, E);
        int kmax = excl ? S : E;
        int nt = nseg * ((kmax + 63) >> 6);
        nb += (nt + CH - 1) / CH;
    }
    return nb;
}

extern "C" void kernel_launch(void* const* d_in, const int* in_sizes, int n_in,
                              void* d_out, int out_size, void* d_ws, size_t ws_size,
                              hipStream_t stream) {
    const float* x  = (const float*)d_in[0];
    const float* W0 = (const float*)d_in[1];
    const float* b0 = (const float*)d_in[2];
    const float* a1 = (const float*)d_in[3];
    const float* W1 = (const float*)d_in[4];
    const float* b1 = (const float*)d_in[5];
    const float* a2 = (const float*)d_in[6];
    const float* W2 = (const float*)d_in[7];
    const float* b2 = (const float*)d_in[8];

    char* ws = (char*)d_ws;
    unsigned short* xf = (unsigned short*)ws;                 // 1 MB
    unsigned short* h0 = (unsigned short*)(ws + (1 << 20));   // 2 MB
    unsigned short* h1 = (unsigned short*)(ws + (3 << 20));   // 2 MB
    float*          pp = (float*)(ws + (5 << 20));            // partials

    // smallest CHUNK whose partial buffer fits the workspace
    int CH = 128;
    int g0 = 0, g1 = 0, g2 = 0;
    const int cands[5] = {8, 16, 32, 64, 128};
    for (int ci = 0; ci < 5; ++ci) {
        int c = cands[ci];
        int a = grid_for(2 * NN, 1, 1, c);
        int bA = grid_for(2 * NN, 2, 0, c);
        int cC = grid_for(NN, 2, 0, c);
        int gmax = a > bA ? a : bA;
        if (cC > gmax) gmax = cC;
        size_t need = (size_t)(5 << 20) + (size_t)gmax * 65536;
        if (need <= ws_size || ci == 4) {
            CH = c; g0 = a; g1 = bA; g2 = cC;
            break;
        }
    }

    fold_k<<<2048, 256, 0, stream>>>(x, xf);

    made_gemm6<true><<<g0, 512, 0, stream>>>(xf, W0, pp, 2 * NN, NN, 1, CH);
    reduce01_k<<<1024, 256, 0, stream>>>(pp, b0, a1, h0, 2 * NN, 1, 1, CH);

    made_gemm6<false><<<g1, 512, 0, stream>>>(h0, W1, pp, 2 * NN, 2 * NN, 2, CH);
    reduce01_k<<<1024, 256, 0, stream>>>(pp, b1, a2, h1, 2 * NN, 2, 0, CH);

    made_gemm6<false><<<g2, 512, 0, stream>>>(h1, W2, pp, NN, 2 * NN, 2, CH);
    reduce2_k<<<2048, 256, 0, stream>>>(pp, b2, (float*)d_out, CH);
}

// Round 7
// 188.099 us; speedup vs baseline: 2.6624x; 1.0203x over previous
//
#include <hip/hip_runtime.h>
#include <hip/hip_bf16.h>
#include <cstddef>
#include <cstdint>

#define NN 4096
#define BB 128

using short8 = __attribute__((ext_vector_type(8))) short;
using f32x4  = __attribute__((ext_vector_type(4))) float;

// visible-prefix limits for folded row r: exclusive = S, inclusive = E
__device__ __forceinline__ void klims(int r, int& S, int& E) {
    if (r == 0) { S = 0; E = 1; return; }
    int j = (31 - __clz(r)) >> 1;
    int g = r >> (2 * j);
    S = g << (2 * j);
    E = (g + 1) << (2 * j);
}

// folded index n -> lattice site (row*64+col)
__device__ __forceinline__ int perm_site(int n) {
    if (n == 0) return 0;
    int j = (31 - __clz(n)) >> 1;
    int g = n >> (2 * j);
    int o = n - (g << (2 * j));
    int side = 1 << j;
    int rr = o >> j, cc = o & (side - 1);
    int i = 5 - j;
    int s = 1 << i, p = 1 << (i + 1);
    int r, c;
    if (g == 1)      { r = s + rr * p; c = s + cc * p; }
    else if (g == 2) { r = s + rr * p; c = cc * p;     }
    else             { r = rr * p;     c = s + cc * p; }
    return r * 64 + c;
}

// lattice site s -> folded index n
__device__ __forceinline__ int inv_site(int s) {
    if (s == 0) return 0;
    int r = s >> 6, c = s & 63;
    int ir = r ? __builtin_ctz(r) : 6;
    int ic = c ? __builtin_ctz(c) : 6;
    int i = ir < ic ? ir : ic;
    int j = 5 - i;
    int rb = (r >> i) & 1, cb = (c >> i) & 1;
    int g = rb ? (cb ? 1 : 2) : 3;
    return (g << (2 * j)) + ((r >> (i + 1)) << j) + (c >> (i + 1));
}

// fragment-order element index for activation storage [k][b] (bf16)
__device__ __forceinline__ size_t fidx(int k, int b) {
    return (size_t)(((k >> 5) * 8 + (b >> 4)) * 512 + ((k >> 2) & 3) * 128 +
                    (b & 15) * 8 + ((k >> 4) & 1) * 4 + (k & 3));
}

__device__ __forceinline__ unsigned short f2bf(float f) {
    __hip_bfloat16 h = __float2bfloat16(f);
    return __builtin_bit_cast(unsigned short, h);
}

// per-tile k-step count (tile-level kmax from its top row), uniform helper
__device__ __forceinline__ int tile_nt(int M, int tile, int nseg, int excl) {
    int r_top = (M - 1 - tile * 128) & (NN - 1);
    int S, E;
    klims(r_top, S, E);
    int kmax = excl ? S : E;
    return nseg * ((kmax + 63) >> 6);
}

// fold: xf_frag[n][b] = x[b][site(n)] as bf16, coalesced reads over x
__global__ void fold_k(const float* __restrict__ x, unsigned short* __restrict__ xf) {
    int gid = blockIdx.x * 256 + threadIdx.x;  // b*4096 + s
    int b = gid >> 12, s = gid & 4095;
    float v = x[gid];
    int n = inv_site(s);
    xf[fidx(n, b)] = f2bf(v);
}

// Masked GEMM, flattened work queue + W-burst supersteps.
// Block = (tile of 128 rows, CHUNK k-steps). 8 waves x 16 rows.
// Superstep = 4 k-steps: issue 16 W dwordx4 back-to-back (1KB/row burst),
// then 4 compute sub-steps. fp32 partial tile written at blockIdx slot.
template <bool EXCL>
__global__ __launch_bounds__(512, 2) void made_gemm7(
        const unsigned short* __restrict__ A, const float* __restrict__ W,
        float* __restrict__ partial, int M, int Ktot, int nseg, int CH) {
    // uniform block -> (tile, chunk) lookup
    int b = (int)blockIdx.x, tile = 0, base = 0, nt = 0;
    for (;;) {
        nt = tile_nt(M, tile, nseg, EXCL ? 1 : 0);
        int cnt = (nt + CH - 1) / CH;
        if (b < base + cnt) break;
        base += cnt;
        ++tile;
    }
    const int nkt = nt / nseg;
    const int t0 = (b - base) * CH;
    const int t1 = (t0 + CH < nt) ? t0 + CH : nt;

    const int tid  = threadIdx.x;
    const int wid  = tid >> 6;
    const int lane = tid & 63;
    const int r0   = M - 128 - tile * 128;
    const int rw0  = r0 + wid * 16;
    const int rch  = rw0 & (NN - 1);
    const int row  = lane & 15;
    const int kq   = lane >> 4;

    int S, E;
    klims(rch + row, S, E);
    const int kl = EXCL ? S : E;        // this lane-row's seg-local prefix limit
    klims(rch, S, E);
    const int wkmin = EXCL ? S : E;     // wave row-0 limit (monotone min)

    f32x4 acc[8] = {};
    const float* wrow = W + (size_t)(rw0 + row) * Ktot + kq * 4;

    float4 wA[4], wB[4], wC[4], wD[4];

#define ISSUE_W(T, WB)                                                        \
    {                                                                         \
        int sg_ = (nseg == 2 && (T) >= nkt) ? 1 : 0;                          \
        const float* wp_ = wrow + sg_ * NN + (((T) - sg_ * nkt) << 6);        \
        WB[0] = *(const float4*)(wp_);                                        \
        WB[1] = *(const float4*)(wp_ + 16);                                   \
        WB[2] = *(const float4*)(wp_ + 32);                                   \
        WB[3] = *(const float4*)(wp_ + 48);                                   \
    }

#define COMPUTE(T, WB)                                                        \
    {                                                                         \
        int sg_ = (nseg == 2 && (T) >= nkt) ? 1 : 0;                          \
        int kb_ = ((T) - sg_ * nkt) << 6;                                     \
        const unsigned short* ab_ =                                           \
            A + (size_t)((sg_ * NN + kb_) >> 5) * 4096 + lane * 8;            \
        short8 av_[16];                                                       \
        _Pragma("unroll")                                                     \
        for (int q_ = 0; q_ < 8; ++q_) {                                      \
            av_[2 * q_]     = *(const short8*)(ab_ + q_ * 512);               \
            av_[2 * q_ + 1] = *(const short8*)(ab_ + 4096 + q_ * 512);        \
        }                                                                     \
        float wv_[16];                                                        \
        _Pragma("unroll")                                                     \
        for (int i_ = 0; i_ < 4; ++i_) {                                      \
            wv_[4 * i_ + 0] = WB[i_].x;                                       \
            wv_[4 * i_ + 1] = WB[i_].y;                                       \
            wv_[4 * i_ + 2] = WB[i_].z;                                       \
            wv_[4 * i_ + 3] = WB[i_].w;                                       \
        }                                                                     \
        if (kb_ + 64 > wkmin) {                                               \
            int k0_ = kb_ + kq * 4;                                           \
            _Pragma("unroll")                                                 \
            for (int i_ = 0; i_ < 4; ++i_) {                                  \
                _Pragma("unroll")                                             \
                for (int j_ = 0; j_ < 4; ++j_)                                \
                    if (k0_ + i_ * 16 + j_ >= kl) wv_[4 * i_ + j_] = 0.0f;    \
            }                                                                 \
        }                                                                     \
        short8 wf0_, wf1_;                                                    \
        _Pragma("unroll")                                                     \
        for (int e_ = 0; e_ < 8; ++e_) {                                      \
            wf0_[e_] = (short)f2bf(wv_[e_]);                                  \
            wf1_[e_] = (short)f2bf(wv_[8 + e_]);                              \
        }                                                                     \
        _Pragma("unroll")                                                     \
        for (int q_ = 0; q_ < 8; ++q_) {                                      \
            acc[q_] = __builtin_amdgcn_mfma_f32_16x16x32_bf16(                \
                wf0_, av_[2 * q_], acc[q_], 0, 0, 0);                         \
            acc[q_] = __builtin_amdgcn_mfma_f32_16x16x32_bf16(                \
                wf1_, av_[2 * q_ + 1], acc[q_], 0, 0, 0);                     \
        }                                                                     \
    }

    {
        int t = t0;
        while (t + 4 <= t1) {
            // W burst: 16 dwordx4 back-to-back -> 1KB contiguous per row
            ISSUE_W(t + 0, wA);
            ISSUE_W(t + 1, wB);
            ISSUE_W(t + 2, wC);
            ISSUE_W(t + 3, wD);
            __builtin_amdgcn_sched_barrier(0);  // keep the burst intact
            COMPUTE(t + 0, wA);
            COMPUTE(t + 1, wB);
            COMPUTE(t + 2, wC);
            COMPUTE(t + 3, wD);
            t += 4;
        }
        while (t < t1) {
            ISSUE_W(t, wA);
            COMPUTE(t, wA);
            ++t;
        }
    }
#undef ISSUE_W
#undef COMPUTE

    // fp32 partial tile [128 rows][128 b] at this block's slot
    float* pc = partial + (size_t)blockIdx.x * 16384 + (wid * 16 + kq * 4) * 128 + row;
#pragma unroll
    for (int q = 0; q < 8; ++q)
#pragma unroll
        for (int i = 0; i < 4; ++i)
            pc[(size_t)i * 128 + q * 16] = acc[q][i];
}

// reduce partial slots + bias + prelu -> bf16 fragment-order activations
__global__ void reduce01_k(const float* __restrict__ p, const float* __restrict__ bias,
                           const float* __restrict__ alpha, unsigned short* __restrict__ h,
                           int M, int nseg, int excl, int CH) {
    int gid = blockIdx.x * 256 + threadIdx.x;   // (M/4)*128 threads
    int m0 = (gid >> 7) << 2;
    int b  = gid & 127;
    int tile_m = (M - 128 - (m0 & ~127)) >> 7;
    int basep = 0, cntm = 0;
    for (int tt = 0; tt <= tile_m; ++tt) {
        int nt = tile_nt(M, tt, nseg, excl);
        int cnt = (nt + CH - 1) / CH;
        if (tt == tile_m) cntm = cnt;
        else basep += cnt;
    }
    const float* ps = p + (size_t)basep * 16384 + (m0 & 127) * 128 + b;
    f32x4 v = {};
    for (int s = 0; s < cntm; ++s) {
        v[0] += ps[0];
        v[1] += ps[128];
        v[2] += ps[256];
        v[3] += ps[384];
        ps += 16384;
    }
    ushort4 st;
    float t;
    t = v[0] + bias[m0 + 0]; t = fmaxf(t, 0.f) + alpha[m0 + 0] * fminf(t, 0.f); st.x = f2bf(t);
    t = v[1] + bias[m0 + 1]; t = fmaxf(t, 0.f) + alpha[m0 + 1] * fminf(t, 0.f); st.y = f2bf(t);
    t = v[2] + bias[m0 + 2]; t = fmaxf(t, 0.f) + alpha[m0 + 2] * fminf(t, 0.f); st.z = f2bf(t);
    t = v[3] + bias[m0 + 3]; t = fmaxf(t, 0.f) + alpha[m0 + 3] * fminf(t, 0.f); st.w = f2bf(t);
    *(ushort4*)&h[fidx(m0, b)] = st;
}

// reduce partial slots + bias + sigmoid + unfold scatter -> out[b][site]
__global__ void reduce2_k(const float* __restrict__ p, const float* __restrict__ b2,
                          float* __restrict__ out, int CH) {
    int gid = blockIdx.x * 256 + threadIdx.x;   // NN*BB threads, n-major
    int n = gid >> 7;
    int b = gid & 127;
    int tile_m = (NN - 128 - (n & ~127)) >> 7;
    int basep = 0, cntm = 0;
    for (int tt = 0; tt <= tile_m; ++tt) {
        int nt = tile_nt(NN, tt, 2, 0);
        int cnt = (nt + CH - 1) / CH;
        if (tt == tile_m) cntm = cnt;
        else basep += cnt;
    }
    const float* ps = p + (size_t)basep * 16384 + (n & 127) * 128 + b;
    float v = 0.0f;
    for (int s = 0; s < cntm; ++s) { v += *ps; ps += 16384; }
    v += b2[n];
    float sg = 1.0f / (1.0f + __expf(-v));
    if (n == 0) sg = 0.5f;
    out[(size_t)b * NN + perm_site(n)] = sg;
}

// ---------------- host ----------------
static inline void h_klims(int r, int& S, int& E) {
    if (r == 0) { S = 0; E = 1; return; }
    int j = (31 - __builtin_clz((unsigned)r)) >> 1;
    int g = r >> (2 * j);
    S = g << (2 * j);
    E = (g + 1) << (2 * j);
}

static inline int grid_for(int M, int nseg, int excl, int CH) {
    int nb = 0;
    for (int tile = 0; tile < M / 128; ++tile) {
        int r_top = (M - 1 - tile * 128) & (NN - 1);
        int S, E;
        h_klims(r_top, S, E);
        int kmax = excl ? S : E;
        int nt = nseg * ((kmax + 63) >> 6);
        nb += (nt + CH - 1) / CH;
    }
    return nb;
}

extern "C" void kernel_launch(void* const* d_in, const int* in_sizes, int n_in,
                              void* d_out, int out_size, void* d_ws, size_t ws_size,
                              hipStream_t stream) {
    const float* x  = (const float*)d_in[0];
    const float* W0 = (const float*)d_in[1];
    const float* b0 = (const float*)d_in[2];
    const float* a1 = (const float*)d_in[3];
    const float* W1 = (const float*)d_in[4];
    const float* b1 = (const float*)d_in[5];
    const float* a2 = (const float*)d_in[6];
    const float* W2 = (const float*)d_in[7];
    const float* b2 = (const float*)d_in[8];

    char* ws = (char*)d_ws;
    unsigned short* xf = (unsigned short*)ws;                 // 1 MB
    unsigned short* h0 = (unsigned short*)(ws + (1 << 20));   // 2 MB
    unsigned short* h1 = (unsigned short*)(ws + (3 << 20));   // 2 MB
    float*          pp = (float*)(ws + (5 << 20));            // partials

    // smallest CHUNK whose partial buffer fits the workspace
    int CH = 128;
    int g0 = 0, g1 = 0, g2 = 0;
    const int cands[5] = {8, 16, 32, 64, 128};
    for (int ci = 0; ci < 5; ++ci) {
        int c = cands[ci];
        int a = grid_for(2 * NN, 1, 1, c);
        int bA = grid_for(2 * NN, 2, 0, c);
        int cC = grid_for(NN, 2, 0, c);
        int gmax = a > bA ? a : bA;
        if (cC > gmax) gmax = cC;
        size_t need = (size_t)(5 << 20) + (size_t)gmax * 65536;
        if (need <= ws_size || ci == 4) {
            CH = c; g0 = a; g1 = bA; g2 = cC;
            break;
        }
    }

    fold_k<<<2048, 256, 0, stream>>>(x, xf);

    made_gemm7<true><<<g0, 512, 0, stream>>>(xf, W0, pp, 2 * NN, NN, 1, CH);
    reduce01_k<<<1024, 256, 0, stream>>>(pp, b0, a1, h0, 2 * NN, 1, 1, CH);

    made_gemm7<false><<<g1, 512, 0, stream>>>(h0, W1, pp, 2 * NN, 2 * NN, 2, CH);
    reduce01_k<<<1024, 256, 0, stream>>>(pp, b1, a2, h1, 2 * NN, 2, 0, CH);

    made_gemm7<false><<<g2, 512, 0, stream>>>(h1, W2, pp, NN, 2 * NN, 2, CH);
    reduce2_k<<<2048, 256, 0, stream>>>(pp, b2, (float*)d_out, CH);
}